// Round 2
// baseline (250.182 us; speedup 1.0000x reference)
//
#include <hip/hip_runtime.h>
#include <math.h>

// ---------------------------------------------------------------------------
// GMM log-likelihood, N=2M x D=16, K=32, out = mean_n logsumexp_k loglik[n,k]
//
// loglik[n,k] = -0.5 (x-mu)^T P_k (x-mu) - 0.5 D log(2pi) - logdet_k + lw_k^2
//             =  sum_{ij} (-0.5 P_ij) x_i x_j  +  (P mu)_i x_i  +  c_k
// i.e. LINEAR in features phi(x) = [ x_i*x_j (256 ordered pairs), x_i (16), pad ]
// => one f16 MFMA GEMM  W[32 x 288] @ phi[288 x 16pts], logsumexp in epilogue.
// All math folded into log2 domain (exp2/log2 native instructions).
// ---------------------------------------------------------------------------

#define LOG_2PI 1.8378770664093453f
#define INV_LN2 1.4426950408889634f
#define LN2_D   0.6931471805599453

typedef float    float4v __attribute__((ext_vector_type(4)));
typedef _Float16 f16x8   __attribute__((ext_vector_type(8)));
typedef _Float16 f16x2   __attribute__((ext_vector_type(2)));

union H8 { f16x8 h8; f16x2 h2[4]; };

#if __has_builtin(__builtin_amdgcn_exp2f)
#define EXP2F(x) __builtin_amdgcn_exp2f(x)
#else
#define EXP2F(x) exp2f(x)
#endif
#if __has_builtin(__builtin_amdgcn_logf)
#define LOG2F(x) __builtin_amdgcn_logf(x)
#else
#define LOG2F(x) log2f(x)
#endif

static __device__ __forceinline__ f16x2 pk2(float a, float b) {
#if __has_builtin(__builtin_amdgcn_cvt_pkrtz)
  // builtin returns __fp16-based vector; bit-identical to _Float16-based f16x2
  return __builtin_bit_cast(f16x2, __builtin_amdgcn_cvt_pkrtz(a, b));
#else
  f16x2 r; r[0] = (_Float16)a; r[1] = (_Float16)b; return r;
#endif
}

// ---------------------------------------------------------------------------
// Setup: per component k (one block each): cov = A A^T, Cholesky L, Linv,
// P = Linv^T Linv, write W in MFMA A-fragment order (f16) + c2[k] (f32).
// A-fragment (16x16x32): lane l holds A[m = l&15][k = 32c + 8*(l>>4) + v].
// Feature index kf: [0,256): (i,j)=(kf>>4, kf&15) -> coeff -0.5*P[i][j]/ln2
//                   [256,272): linear i=kf-256    -> coeff (P mu)_i/ln2
//                   [272,288): zero pad
// ---------------------------------------------------------------------------
__global__ void setup_kernel(const float* __restrict__ means,
                             const float* __restrict__ cov_parts,
                             const float* __restrict__ log_weights,
                             _Float16* __restrict__ W,
                             float* __restrict__ c2)
{
  const int k = blockIdx.x;      // component 0..31
  const int i = threadIdx.x;     // 0..63, active < 16
  const int t = k >> 4, m = k & 15;

  __shared__ float sA[16][17];   // A, later Linv
  __shared__ float sC[16][17];   // cov -> L (lower)
  __shared__ float sMu[16];
  __shared__ float sR[16];       // r = P mu

  if (i < 16) {
    #pragma unroll
    for (int j = 0; j < 16; ++j) sA[i][j] = cov_parts[(k*16 + i)*16 + j];
    sMu[i] = means[k*16 + i];
  }
  __syncthreads();

  // cov[i][j] = sum_l A[i][l] A[j][l]
  if (i < 16) {
    #pragma unroll
    for (int j = 0; j < 16; ++j) {
      float acc = 0.f;
      #pragma unroll
      for (int l = 0; l < 16; ++l) acc += sA[i][l] * sA[j][l];
      sC[i][j] = acc;
    }
  }
  __syncthreads();

  // in-place Cholesky (lower) on sC
  for (int j = 0; j < 16; ++j) {
    if (i == j) {
      float d = sC[j][j];
      for (int l = 0; l < j; ++l) d -= sC[j][l]*sC[j][l];
      sC[j][j] = sqrtf(d);
    }
    __syncthreads();
    if (i < 16 && i > j) {
      float a = sC[i][j];
      for (int l = 0; l < j; ++l) a -= sC[i][l]*sC[j][l];
      sC[i][j] = a / sC[j][j];
    }
    __syncthreads();
  }

  // Linv column i (forward solve L y = e_i), store into sA[:, i]
  if (i < 16) {
    float y[16];
    #pragma unroll
    for (int r = 0; r < 16; ++r) {
      float a = (r == i) ? 1.f : 0.f;
      #pragma unroll
      for (int l = 0; l < r; ++l) a -= sC[r][l] * y[l];
      y[r] = a / sC[r][r];       // rows r < i come out exactly 0
    }
    #pragma unroll
    for (int r = 0; r < 16; ++r) sA[r][i] = y[r];
  }
  __syncthreads();

  // P row i = sum_l Linv[l][i] * Linv[l][:] ; write W coefficients
  if (i < 16) {
    float p[16];
    #pragma unroll
    for (int j = 0; j < 16; ++j) {
      float acc = 0.f;
      #pragma unroll
      for (int l = 0; l < 16; ++l) acc += sA[l][i] * sA[l][j];
      p[j] = acc;
    }
    float ri = 0.f;
    #pragma unroll
    for (int j = 0; j < 16; ++j) ri += p[j] * sMu[j];
    sR[i] = ri;

    #pragma unroll
    for (int j = 0; j < 16; ++j) {
      int kf = 16*i + j;
      int c = kf >> 5, g = (kf >> 3) & 3, v = kf & 7;
      W[(size_t)((t*9 + c)*64 + g*16 + m)*8 + v] =
          (_Float16)(-0.5f * INV_LN2 * p[j]);
    }
    { // linear term
      int g = i >> 3, v = i & 7;
      W[(size_t)((t*9 + 8)*64 + g*16 + m)*8 + v] = (_Float16)(INV_LN2 * ri);
    }
    { // zero pad
      int g = 2 + (i >> 3), v = i & 7;
      W[(size_t)((t*9 + 8)*64 + g*16 + m)*8 + v] = (_Float16)0.f;
    }
  }
  __syncthreads();

  if (i == 0) {
    float logdet = 0.f;
    #pragma unroll
    for (int j = 0; j < 16; ++j) logdet += __logf(sC[j][j]);
    float mupmu = 0.f;
    #pragma unroll
    for (int j = 0; j < 16; ++j) mupmu += sMu[j] * sR[j];
    float lw = log_weights[k];
    c2[k] = INV_LN2 * (-0.5f*(mupmu + 16.f*LOG_2PI) - logdet + lw*lw);
  }
}

// ---------------------------------------------------------------------------
// Main: each wave owns 16-point tiles (grid-stride). Per tile:
//   B-frag: lane computes its 8 features of point p=lane&15 (all x in regs),
//   18 chained mfma_f32_16x16x32_f16 (W held in 72 VGPRs),
//   C layout col=lane&15(point), row=(lane>>4)*4+reg(comp) => lane has 8 of
//   the 32 logliks of its point; logsumexp via xor16/xor32 shuffles.
// Each point is produced by 4 lanes -> final scale has /4.
// ---------------------------------------------------------------------------
__global__ __launch_bounds__(256) void main_kernel(
    const float* __restrict__ data,
    const _Float16* __restrict__ W,
    const float* __restrict__ c2,
    float* __restrict__ partials,
    int npts, int ntiles)
{
  const int lane = threadIdx.x & 63;
  const int p16  = lane & 15;
  const int g    = lane >> 4;
  const int gwave  = (int)((blockIdx.x * blockDim.x + threadIdx.x) >> 6);
  const int nwaves = (int)((gridDim.x * blockDim.x) >> 6);

  f16x8 Wf[2][9];
  #pragma unroll
  for (int t = 0; t < 2; ++t)
    #pragma unroll
    for (int c = 0; c < 9; ++c)
      Wf[t][c] = *(const f16x8*)(W + (size_t)((t*9 + c)*64 + lane)*8);

  float4v c2a = *(const float4v*)(c2 + 4*g);        // comps 4g..4g+3
  float4v c2b = *(const float4v*)(c2 + 16 + 4*g);   // comps 16+4g..

  const bool glo = (g & 1) != 0;
  const bool ghi = (g >= 2);

  float accsum = 0.f;

  for (int tile = gwave; tile < ntiles; tile += nwaves) {
    int pt = tile*16 + p16;
    bool valid = (pt < npts);
    const float* xp = data + (size_t)(valid ? pt : 0) * 16;
    float4v xv0 = *(const float4v*)(xp);
    float4v xv1 = *(const float4v*)(xp + 4);
    float4v xv2 = *(const float4v*)(xp + 8);
    float4v xv3 = *(const float4v*)(xp + 12);
    float x[16];
    #pragma unroll
    for (int j = 0; j < 4; ++j) {
      x[j] = xv0[j]; x[4+j] = xv1[j]; x[8+j] = xv2[j]; x[12+j] = xv3[j];
    }
    // second-factor half: kf&15 = 8*(g&1)+j
    float xlow[8];
    #pragma unroll
    for (int j = 0; j < 8; ++j) xlow[j] = glo ? x[8+j] : x[j];

    float4v acc0 = {0.f, 0.f, 0.f, 0.f};
    float4v acc1 = {0.f, 0.f, 0.f, 0.f};

    #pragma unroll
    for (int c = 0; c < 8; ++c) {
      // first factor index: kf>>4 = 2c + (g>>1)
      float xi = ghi ? x[2*c+1] : x[2*c];
      H8 b;
      #pragma unroll
      for (int j = 0; j < 4; ++j)
        b.h2[j] = pk2(xi * xlow[2*j], xi * xlow[2*j+1]);
      acc0 = __builtin_amdgcn_mfma_f32_16x16x32_f16(Wf[0][c], b.h8, acc0, 0, 0, 0);
      acc1 = __builtin_amdgcn_mfma_f32_16x16x32_f16(Wf[1][c], b.h8, acc1, 0, 0, 0);
    }
    { // chunk 8: linear features (groups 0,1), zero pad (groups 2,3)
      H8 b;
      #pragma unroll
      for (int j = 0; j < 4; ++j) {
        float f0 = ghi ? 0.f : xlow[2*j];
        float f1 = ghi ? 0.f : xlow[2*j+1];
        b.h2[j] = pk2(f0, f1);
      }
      acc0 = __builtin_amdgcn_mfma_f32_16x16x32_f16(Wf[0][8], b.h8, acc0, 0, 0, 0);
      acc1 = __builtin_amdgcn_mfma_f32_16x16x32_f16(Wf[1][8], b.h8, acc1, 0, 0, 0);
    }

    // epilogue: 8 logliks (log2 domain) for point p16 live in this lane
    float v[8];
    #pragma unroll
    for (int r = 0; r < 4; ++r) { v[r] = acc0[r] + c2a[r]; v[4+r] = acc1[r] + c2b[r]; }
    float mx = v[0];
    #pragma unroll
    for (int r = 1; r < 8; ++r) mx = fmaxf(mx, v[r]);
    mx = fmaxf(mx, __shfl_xor(mx, 16, 64));
    mx = fmaxf(mx, __shfl_xor(mx, 32, 64));
    float s = 0.f;
    #pragma unroll
    for (int r = 0; r < 8; ++r) s += EXP2F(v[r] - mx);
    s += __shfl_xor(s, 16, 64);
    s += __shfl_xor(s, 32, 64);
    float lse = mx + LOG2F(s);          // log2-domain LSE, counted 4x/point
    accsum += valid ? lse : 0.f;
  }

  #pragma unroll
  for (int off = 1; off <= 32; off <<= 1)
    accsum += __shfl_xor(accsum, off, 64);

  __shared__ float wsum[4];
  const int wid = (int)(threadIdx.x >> 6);
  if (lane == 0) wsum[wid] = accsum;
  __syncthreads();
  if (threadIdx.x == 0)
    partials[blockIdx.x] = wsum[0] + wsum[1] + wsum[2] + wsum[3];
}

// ---------------------------------------------------------------------------
__global__ void reduce_kernel(const float* __restrict__ partials, int n,
                              float* __restrict__ out, double scale)
{
  __shared__ double sd[256];
  double a = 0.0;
  for (int idx = threadIdx.x; idx < n; idx += 256) a += (double)partials[idx];
  sd[threadIdx.x] = a;
  __syncthreads();
  for (int s = 128; s > 0; s >>= 1) {
    if ((int)threadIdx.x < s) sd[threadIdx.x] += sd[threadIdx.x + s];
    __syncthreads();
  }
  if (threadIdx.x == 0) out[0] = (float)(sd[0] * scale);
}

extern "C" void kernel_launch(void* const* d_in, const int* in_sizes, int n_in,
                              void* d_out, int out_size, void* d_ws, size_t ws_size,
                              hipStream_t stream)
{
  const float* data        = (const float*)d_in[0];
  const float* means       = (const float*)d_in[1];
  const float* cov_parts   = (const float*)d_in[2];
  const float* log_weights = (const float*)d_in[3];

  const int npts   = in_sizes[0] / 16;
  const int ntiles = (npts + 15) / 16;

  _Float16* W      = (_Float16*)d_ws;                          // 2*9*64*8 halfs = 18432 B
  float*    c2     = (float*)((char*)d_ws + (size_t)2*9*64*8*sizeof(_Float16));
  float*    partials = c2 + 32;

  const int GRID = 1024, BLOCK = 256;
  setup_kernel<<<32, 64, 0, stream>>>(means, cov_parts, log_weights, W, c2);
  main_kernel<<<GRID, BLOCK, 0, stream>>>(data, W, c2, partials, npts, ntiles);
  reduce_kernel<<<1, 256, 0, stream>>>(partials, GRID, (float*)d_out,
                                       LN2_D / (4.0 * (double)npts));
}

// Round 3
// 204.398 us; speedup vs baseline: 1.2240x; 1.2240x over previous
//
#include <hip/hip_runtime.h>
#include <math.h>

// ---------------------------------------------------------------------------
// GMM log-likelihood, N=2M x D=16, K=32, out = mean_n logsumexp_k loglik[n,k]
//
// loglik[n,k] = sum_{ij} (-0.5 P_ij) x_i x_j + (P mu)_i x_i + c_k  (log2 domain)
// LINEAR in features phi(x) = [ x_i*x_j (256), x_i (16) ]  (K=272, 17 chunks)
// One f16 MFMA chain per 32-point tile: W[32 x 272] @ phi[272 x 32pts] using
// mfma_f32_32x32x16_f16 (M=32 = all components). C layout (HW-verified):
// col = lane&31 (point), row = (reg&3)+8*(reg>>2)+4*(lane>>5) (component).
// Lane pair (l, l^32) holds all 32 comps of point l&31; pairing via
// v_permlane32_swap (VALU-only — NO ds_bpermute; R2 showed shuffles cost
// ~62 conflict-cycles each).
// __launch_bounds__(256,3): R2's default bounds capped VGPR at 64 and the
// compiler re-loaded W every tile; 3 waves/EU allows ~170 VGPR so W (68
// regs) + acc (16) + prefetch stay resident.
// ---------------------------------------------------------------------------

#define LOG_2PI 1.8378770664093453f
#define INV_LN2 1.4426950408889634f
#define LN2_D   0.6931471805599453

typedef float    float4v __attribute__((ext_vector_type(4)));
typedef float    f32x16  __attribute__((ext_vector_type(16)));
typedef _Float16 f16x8   __attribute__((ext_vector_type(8)));
typedef _Float16 f16x2   __attribute__((ext_vector_type(2)));

union H8 { f16x8 h8; f16x2 h2[4]; };

#if __has_builtin(__builtin_amdgcn_exp2f)
#define EXP2F(x) __builtin_amdgcn_exp2f(x)
#else
#define EXP2F(x) exp2f(x)
#endif
#if __has_builtin(__builtin_amdgcn_logf)
#define LOG2F(x) __builtin_amdgcn_logf(x)
#else
#define LOG2F(x) log2f(x)
#endif

static __device__ __forceinline__ f16x2 pk2(float a, float b) {
#if __has_builtin(__builtin_amdgcn_cvt_pkrtz)
  return __builtin_bit_cast(f16x2, __builtin_amdgcn_cvt_pkrtz(a, b));
#else
  f16x2 r; r[0] = (_Float16)a; r[1] = (_Float16)b; return r;
#endif
}

// value of x in partner lane (lane ^ 32), VALU-only on gfx950
static __device__ __forceinline__ float partner32(float x, bool lo) {
#if __has_builtin(__builtin_amdgcn_permlane32_swap)
  typedef unsigned u32x2 __attribute__((ext_vector_type(2)));
  unsigned u = __builtin_bit_cast(unsigned, x);
  u32x2 r = __builtin_amdgcn_permlane32_swap(u, u, false, false);
  // r[0]: lanes>=32 hold x[l-32]; r[1]: lanes<32 hold x[l+32]
  return __builtin_bit_cast(float, lo ? r[1] : r[0]);
#else
  return __shfl_xor(x, 32, 64);
#endif
}

// ---------------------------------------------------------------------------
// Setup: per component k: cov = A A^T, Cholesky L, Linv, P = Linv^T Linv.
// W in 32x32x16 A-frag order: lane l holds A[m=l&31][k16 = 8*(l>>5)+v],
// chunk c covers feature k = 16c + 8h + v.
// Feature k: [0,256): (i,j)=(k>>4,k&15) -> -0.5/ln2 * P[i][j]
//            [256,272): i=k-256 -> (P mu)_i / ln2.  c2[k] f32 separately.
// ---------------------------------------------------------------------------
__global__ void setup_kernel(const float* __restrict__ means,
                             const float* __restrict__ cov_parts,
                             const float* __restrict__ log_weights,
                             _Float16* __restrict__ W,
                             float* __restrict__ c2)
{
  const int k = blockIdx.x;      // component 0..31
  const int i = threadIdx.x;     // one wave; active < 16

  __shared__ float sA[16][17];   // A, later Linv
  __shared__ float sC[16][17];   // cov -> L (lower)
  __shared__ float sMu[16];
  __shared__ float sR[16];       // r = P mu

  if (i < 16) {
    #pragma unroll
    for (int j = 0; j < 16; ++j) sA[i][j] = cov_parts[(k*16 + i)*16 + j];
    sMu[i] = means[k*16 + i];
  }
  __syncthreads();

  if (i < 16) {
    #pragma unroll
    for (int j = 0; j < 16; ++j) {
      float acc = 0.f;
      #pragma unroll
      for (int l = 0; l < 16; ++l) acc += sA[i][l] * sA[j][l];
      sC[i][j] = acc;
    }
  }
  __syncthreads();

  // in-place Cholesky (lower)
  for (int j = 0; j < 16; ++j) {
    if (i == j) {
      float d = sC[j][j];
      for (int l = 0; l < j; ++l) d -= sC[j][l]*sC[j][l];
      sC[j][j] = sqrtf(d);
    }
    __syncthreads();
    if (i < 16 && i > j) {
      float a = sC[i][j];
      for (int l = 0; l < j; ++l) a -= sC[i][l]*sC[j][l];
      sC[i][j] = a / sC[j][j];
    }
    __syncthreads();
  }

  // Linv column i -> sA[:, i]
  if (i < 16) {
    float y[16];
    #pragma unroll
    for (int r = 0; r < 16; ++r) {
      float a = (r == i) ? 1.f : 0.f;
      #pragma unroll
      for (int l = 0; l < r; ++l) a -= sC[r][l] * y[l];
      y[r] = a / sC[r][r];
    }
    #pragma unroll
    for (int r = 0; r < 16; ++r) sA[r][i] = y[r];
  }
  __syncthreads();

  if (i < 16) {
    float p[16];
    #pragma unroll
    for (int j = 0; j < 16; ++j) {
      float acc = 0.f;
      #pragma unroll
      for (int l = 0; l < 16; ++l) acc += sA[l][i] * sA[l][j];
      p[j] = acc;
    }
    float ri = 0.f;
    #pragma unroll
    for (int j = 0; j < 16; ++j) ri += p[j] * sMu[j];
    sR[i] = ri;

    // quad coeffs: chunk c = i, within-chunk index j: h=j>>3, v=j&7,
    // A-frag lane = k + 32h
    #pragma unroll
    for (int j = 0; j < 16; ++j) {
      W[(size_t)(i*64 + (k + 32*(j >> 3)))*8 + (j & 7)] =
          (_Float16)(-0.5f * INV_LN2 * p[j]);
    }
    // linear coeff: chunk 16, within-chunk index i
    W[(size_t)(16*64 + (k + 32*(i >> 3)))*8 + (i & 7)] =
        (_Float16)(INV_LN2 * ri);
  }
  __syncthreads();

  if (i == 0) {
    float logdet = 0.f;
    #pragma unroll
    for (int j = 0; j < 16; ++j) logdet += __logf(sC[j][j]);
    float mupmu = 0.f;
    #pragma unroll
    for (int j = 0; j < 16; ++j) mupmu += sMu[j] * sR[j];
    float lw = log_weights[k];
    c2[k] = INV_LN2 * (-0.5f*(mupmu + 16.f*LOG_2PI) - logdet + lw*lw);
  }
}

// ---------------------------------------------------------------------------
// Main: wave processes 32-point tiles (grid-stride). Lane owns point
// pt = tile*32 + (lane&31); its 16 floats held in regs; 17 chunks of
// packed-f16 features feed one chained 32x32x16 MFMA. Epilogue: 16 comps in
// this lane + 16 in partner lane -> LSE with one permlane32 exchange.
// Both lanes of a pair accumulate the same lse -> final scale /2.
// ---------------------------------------------------------------------------
__global__ __launch_bounds__(256, 3) void main_kernel(
    const float* __restrict__ data,
    const _Float16* __restrict__ W,
    const float* __restrict__ c2,
    float* __restrict__ partials,
    int npts, int ntiles)
{
  const int lane = threadIdx.x & 63;
  const int n32  = lane & 31;
  const bool lo  = lane < 32;          // lane>>5 == 0
  const int h    = lo ? 0 : 1;
  const int gwave  = (int)((blockIdx.x * blockDim.x + threadIdx.x) >> 6);
  const int nwaves = (int)((gridDim.x * blockDim.x) >> 6);

  // W fragments: 17 chunks x 4 VGPR = 68 VGPRs, loop-invariant
  f16x8 Wf[17];
  #pragma unroll
  for (int c = 0; c < 17; ++c)
    Wf[c] = *(const f16x8*)(W + (size_t)(c*64 + lane)*8);

  // c2 for this lane's 16 C-rows: row = (r&3) + 8*(r>>2) + 4*h
  float c2r[16];
  #pragma unroll
  for (int r = 0; r < 16; ++r)
    c2r[r] = c2[(r & 3) + 8*(r >> 2) + 4*h];

  float accsum = 0.f;

  // software-pipelined point loads
  float4v p0, p1, p2, p3;
  if (gwave < ntiles) {
    const float* xp = data + ((size_t)gwave*32 + n32)*16;
    p0 = *(const float4v*)(xp);
    p1 = *(const float4v*)(xp + 4);
    p2 = *(const float4v*)(xp + 8);
    p3 = *(const float4v*)(xp + 12);
  }

  for (int tile = gwave; tile < ntiles; tile += nwaves) {
    float x[16];
    #pragma unroll
    for (int j = 0; j < 4; ++j) {
      x[j] = p0[j]; x[4+j] = p1[j]; x[8+j] = p2[j]; x[12+j] = p3[j];
    }
    int nt = tile + nwaves;
    if (nt < ntiles) {                  // wave-uniform, prefetch next tile
      const float* xp = data + ((size_t)nt*32 + n32)*16;
      p0 = *(const float4v*)(xp);
      p1 = *(const float4v*)(xp + 4);
      p2 = *(const float4v*)(xp + 8);
      p3 = *(const float4v*)(xp + 12);
    }

    // second-factor half (j = 8h + 2t..): packed once per tile
    f16x2 xselh[4];
    #pragma unroll
    for (int j = 0; j < 4; ++j) {
      unsigned ulo = __builtin_bit_cast(unsigned, pk2(x[2*j],   x[2*j+1]));
      unsigned uhi = __builtin_bit_cast(unsigned, pk2(x[8+2*j], x[9+2*j]));
      xselh[j] = __builtin_bit_cast(f16x2, lo ? ulo : uhi);
    }

    f32x16 acc;
    #pragma unroll
    for (int r = 0; r < 16; ++r) acc[r] = 0.f;

    #pragma unroll
    for (int c = 0; c < 16; ++c) {      // quad chunks: feature = x_c * xsel
      f16x2 xi2 = pk2(x[c], x[c]);
      H8 b;
      #pragma unroll
      for (int j = 0; j < 4; ++j) b.h2[j] = xi2 * xselh[j];  // v_pk_mul_f16
      acc = __builtin_amdgcn_mfma_f32_32x32x16_f16(Wf[c], b.h8, acc, 0, 0, 0);
    }
    {                                   // linear chunk: feature = xsel
      H8 b;
      #pragma unroll
      for (int j = 0; j < 4; ++j) b.h2[j] = xselh[j];
      acc = __builtin_amdgcn_mfma_f32_32x32x16_f16(Wf[16], b.h8, acc, 0, 0, 0);
    }

    // epilogue: 16 comps here + 16 in partner lane
    float v[16];
    #pragma unroll
    for (int r = 0; r < 16; ++r) v[r] = acc[r] + c2r[r];
    float m = v[0];
    #pragma unroll
    for (int r = 1; r < 16; ++r) m = fmaxf(m, v[r]);
    m = fmaxf(m, partner32(m, lo));
    float s = 0.f;
    #pragma unroll
    for (int r = 0; r < 16; ++r) s += EXP2F(v[r] - m);
    s += partner32(s, lo);
    accsum += m + LOG2F(s);             // counted 2x per point
  }

  #pragma unroll
  for (int off = 1; off <= 32; off <<= 1)
    accsum += __shfl_xor(accsum, off, 64);

  __shared__ float wsum[4];
  const int wid = (int)(threadIdx.x >> 6);
  if ((threadIdx.x & 63) == 0) wsum[wid] = accsum;
  __syncthreads();
  if (threadIdx.x == 0)
    partials[blockIdx.x] = wsum[0] + wsum[1] + wsum[2] + wsum[3];
}

// ---------------------------------------------------------------------------
__global__ void reduce_kernel(const float* __restrict__ partials, int n,
                              float* __restrict__ out, double scale)
{
  __shared__ double sd[256];
  double a = 0.0;
  for (int idx = threadIdx.x; idx < n; idx += 256) a += (double)partials[idx];
  sd[threadIdx.x] = a;
  __syncthreads();
  for (int s = 128; s > 0; s >>= 1) {
    if ((int)threadIdx.x < s) sd[threadIdx.x] += sd[threadIdx.x + s];
    __syncthreads();
  }
  if (threadIdx.x == 0) out[0] = (float)(sd[0] * scale);
}

extern "C" void kernel_launch(void* const* d_in, const int* in_sizes, int n_in,
                              void* d_out, int out_size, void* d_ws, size_t ws_size,
                              hipStream_t stream)
{
  const float* data        = (const float*)d_in[0];
  const float* means       = (const float*)d_in[1];
  const float* cov_parts   = (const float*)d_in[2];
  const float* log_weights = (const float*)d_in[3];

  const int npts   = in_sizes[0] / 16;
  const int ntiles = npts / 32;        // N = 2,000,000 is divisible by 32

  _Float16* W      = (_Float16*)d_ws;                          // 17*64*8 halfs
  float*    c2     = (float*)((char*)d_ws + (size_t)17*64*8*sizeof(_Float16));
  float*    partials = c2 + 32;

  const int GRID = 1536, BLOCK = 256;  // 3 blocks/CU resident -> 2 full rounds
  setup_kernel<<<32, 64, 0, stream>>>(means, cov_parts, log_weights, W, c2);
  main_kernel<<<GRID, BLOCK, 0, stream>>>(data, W, c2, partials, npts, ntiles);
  reduce_kernel<<<1, 256, 0, stream>>>(partials, GRID, (float*)d_out,
                                       LN2_D / (2.0 * (double)npts));
}